// Round 9
// baseline (334.942 us; speedup 1.0000x reference)
//
#include <hip/hip_runtime.h>
#include <hip/hip_bf16.h>
#include <stdint.h>

#define NN 50000     // nodes
#define NE 640000    // edges
#define NR 8         // relations
#define NK (NR * NN) // 400000 (rel,dst) keys
#define NPB 391      // scan blocks = ceil(NK/1024)

typedef short bf16x8 __attribute__((ext_vector_type(8)));
typedef float f32x4  __attribute__((ext_vector_type(4)));

__device__ __forceinline__ unsigned short f2bf(float f) {
    union { float f; unsigned u; } v; v.f = f;
    unsigned r = v.u + 0x7FFF + ((v.u >> 16) & 1);
    return (unsigned short)(r >> 16);
}

// ---------------- merged prep: cvt + prepW1 + prepW2 + HIST (counts pre-zeroed) ----------------
__global__ __launch_bounds__(256) void prep0_kernel(
        const float* __restrict__ X,
        const float* __restrict__ W1, const float* __restrict__ W1s,
        const float* __restrict__ W2, const float* __restrict__ W2s,
        const int* __restrict__ dst, const int* __restrict__ et,
        unsigned short* __restrict__ Xbf,
        unsigned short* __restrict__ W1T, unsigned short* __restrict__ W2T,
        int* __restrict__ counts) {
    const int gid = blockIdx.x * 256 + threadIdx.x;
    const int gsz = gridDim.x * 256;

    // histogram atomics issued first (latency overlaps streaming below)
    for (int e = gid; e < NE; e += gsz)
        atomicAdd(&counts[et[e] * NN + dst[e]], 1);

    // cvt X -> bf16, 8 floats per unit
    for (int i = gid; i < NN * 16; i += gsz) {
        const float4* pp = (const float4*)X + (size_t)i * 2;
        float4 a = pp[0], b = pp[1];
        uint4 o;
        o.x = (unsigned)f2bf(a.x) | ((unsigned)f2bf(a.y) << 16);
        o.y = (unsigned)f2bf(a.z) | ((unsigned)f2bf(a.w) << 16);
        o.z = (unsigned)f2bf(b.x) | ((unsigned)f2bf(b.y) << 16);
        o.w = (unsigned)f2bf(b.z) | ((unsigned)f2bf(b.w) << 16);
        ((uint4*)Xbf)[i] = o;
    }

    // W1T[(r*128+o)][k], r==8 -> W1s
    for (int i = gid; i < 9 * 128 * 128; i += gsz) {
        int k = i & 127, c = i >> 7;
        int r = c >> 7, o = c & 127;
        float v = (r < 8) ? W1[((size_t)r * 128 + k) * 128 + o]
                          : W1s[(size_t)k * 128 + o];
        W1T[i] = f2bf(v);
    }

    // W2T[(r*64+o)][k], r==8 -> W2s
    for (int i = gid; i < 9 * 64 * 128; i += gsz) {
        int k = i & 127, c = i >> 7;
        int r = c >> 6, o = c & 63;
        float v = (r < 8) ? W2[((size_t)r * 128 + k) * 64 + o]
                          : W2s[(size_t)k * 64 + o];
        W2T[i] = f2bf(v);
    }
}

// ---------------- fused scan: local scan + cooperative base sum (1 launch) ----------------
// Block b: base = sum(counts[0 .. b*1024)) computed by all 16 waves (coalesced,
// counts is 1.6MB L2-hot), local exclusive scan of its own 1024 chunk, then
// offsets/cursor = base + local_excl.
__global__ __launch_bounds__(1024) void scanfused_kernel(const int* __restrict__ counts,
                                                         int* __restrict__ offsets,
                                                         int* __restrict__ cursor, int n) {
    __shared__ int ws[16];
    __shared__ int wbase[16];
    __shared__ int wsum[16];
    __shared__ int base_sh;
    const int t = threadIdx.x, b = blockIdx.x;
    const int i = b * 1024 + t;
    const int lane = t & 63, wid = t >> 6;

    // cooperative partial sum of counts[0 .. b*1024)
    int acc = 0;
    for (int j = t; j < b * 1024; j += 1024) acc += counts[j];
    #pragma unroll
    for (int d = 32; d > 0; d >>= 1) acc += __shfl_down(acc, d, 64);
    if (lane == 0) wsum[wid] = acc;

    // local scan of own chunk
    int v = (i < n) ? counts[i] : 0;
    int incl = v;
    #pragma unroll
    for (int d = 1; d < 64; d <<= 1) {
        int nv = __shfl_up(incl, d, 64);
        if (lane >= d) incl += nv;
    }
    if (lane == 63) ws[wid] = incl;
    __syncthreads();
    if (t < 16) {
        int s = ws[t], si = s;
        #pragma unroll
        for (int d = 1; d < 16; d <<= 1) {
            int nv = __shfl_up(si, d, 16);
            if (t >= d) si += nv;
        }
        wbase[t] = si - s;
    }
    if (t == 16) {
        int s = 0;
        #pragma unroll
        for (int j = 0; j < 16; j++) s += wsum[j];
        base_sh = s;
    }
    __syncthreads();

    if (i < n) {
        int excl = base_sh + wbase[wid] + incl - v;
        offsets[i] = excl;
        cursor[i]  = excl;
    }
    if (b == 0 && t == 0) offsets[NK] = NE;
}

__global__ void fill2_kernel(const int* __restrict__ src, const int* __restrict__ dst,
                             const int* __restrict__ et, int* __restrict__ cursor,
                             int* __restrict__ esrc) {
    int e = blockIdx.x * 256 + threadIdx.x;
    if (e < NE) {
        int pos = atomicAdd(&cursor[et[e] * NN + dst[e]], 1);
        esrc[pos] = src[e];
    }
}

// ---------------- Fused aggregate + transform layer ----------------
// FROZEN: verified RB=64 shape (80.2 us/L1 measured r8). Per block: 64 dst
// nodes, 256 threads. Edges sorted by (rel,dst): atomic-free aggregation.
// Thread t owns dst row (t>>2), column group (t&3): 32 cols in registers over
// its segment, packed to bf16 into the XOR-swizzled Asw. MFMA-accumulates
// C[64][NOUT] += agg_r @ W[r]^T across r=0..7 plus self (idx 8).
template<int NOUT, bool RELU, bool OUTBF16>
__global__ __launch_bounds__(256) void fused_layer(
        const unsigned short* __restrict__ A,    // [M][128] bf16 node features
        const unsigned short* __restrict__ WT,   // [9*NOUT][128] bf16
        const float* __restrict__ bias,          // [NOUT]
        const int* __restrict__ off2,            // [NK+1]
        const int* __restrict__ esrc,            // [NE] src sorted by (rel,dst)
        void* __restrict__ outp, int M) {
    constexpr int CW = NOUT / 4;      // cols per wave (MFMA)
    constexpr int NJ = CW / 16;       // n-tiles per wave
    __shared__ unsigned short Asw[64 * 128];    // swizzled bf16 A-operand (16 KB)

    const int t = threadIdx.x;
    const int n0 = blockIdx.x * 64;
    const int bm = (M - n0 < 64) ? (M - n0) : 64;
    const int lane = t & 63;
    const int w = t >> 6;
    const int r15 = lane & 15;
    const int q = lane >> 4;

    const int key = t >> 2;          // local dst row 0..63
    const int sub = t & 3;           // col group: uints [sub*16, sub*16+16)
    const int kk = n0 + key;
    const bool kv = (kk < M);

    f32x4 acc[4][NJ] = {};

    auto do_mfma = [&](int rr) {
        #pragma unroll
        for (int ks = 0; ks < 4; ks++) {
            int c = (ks * 4 + q) ^ r15;
            bf16x8 af[4];
            #pragma unroll
            for (int i = 0; i < 4; i++)
                af[i] = *(const bf16x8*)((const char*)Asw + (i * 16 + r15) * 256 + (c << 4));
            #pragma unroll
            for (int j = 0; j < NJ; j++) {
                bf16x8 bf = *(const bf16x8*)(WT +
                    ((size_t)(rr * NOUT + w * CW + j * 16 + r15) << 7) + ks * 32 + q * 8);
                #pragma unroll
                for (int i = 0; i < 4; i++)
                    acc[i][j] = __builtin_amdgcn_mfma_f32_16x16x32_bf16(af[i], bf, acc[i][j], 0, 0, 0);
            }
        }
    };

    // prefetch relation-0 segment bounds (off critical path of pass 0)
    int e0 = kv ? off2[kk] : 0;
    int e1 = kv ? off2[kk + 1] : 0;

    // ---- self pass (K-chunk index 8): Asw = own feature rows ----
    #pragma unroll
    for (int kc = 0; kc < 4; kc++) {
        int g = t + kc * 256;           // 1024 chunks = 64 rows x 16
        int row = g >> 4, c = g & 15;
        uint4 v = make_uint4(0, 0, 0, 0);
        if (row < bm) v = *(const uint4*)(A + ((size_t)(n0 + row) << 7) + c * 8);
        *(uint4*)((char*)Asw + row * 256 + ((c ^ (row & 15)) << 4)) = v;
    }
    __syncthreads();
    do_mfma(8);

    // ---- relation passes ----
    for (int r = 0; r < 8; r++) {
        // prefetch next relation's bounds (consumed next iteration)
        int e0n = 0, e1n = 0;
        if (r < 7 && kv) {
            e0n = off2[(r + 1) * NN + kk];
            e1n = off2[(r + 1) * NN + kk + 1];
        }

        // register-accumulate own segment (no LDS touched -> overlaps prior MFMA)
        float a[32];
        #pragma unroll
        for (int i = 0; i < 32; i++) a[i] = 0.f;
        for (int e = e0; e < e1; ++e) {
            int s = esrc[e];
            const uint4* rp = (const uint4*)((const unsigned*)A + ((size_t)s << 6) + sub * 16);
            #pragma unroll
            for (int u4 = 0; u4 < 4; ++u4) {
                uint4 v = rp[u4];
                unsigned uu[4] = {v.x, v.y, v.z, v.w};
                #pragma unroll
                for (int j = 0; j < 4; ++j) {
                    a[u4 * 8 + j * 2 + 0] += __uint_as_float(uu[j] << 16);
                    a[u4 * 8 + j * 2 + 1] += __uint_as_float(uu[j] & 0xffff0000u);
                }
            }
        }
        __syncthreads();   // all waves done reading Asw from previous MFMA

        // pack to bf16 and write 4 swizzled 16B chunks (c = sub*4+c4)
        #pragma unroll
        for (int c4 = 0; c4 < 4; ++c4) {
            uint4 pv;
            pv.x = (unsigned)f2bf(a[c4 * 8 + 0]) | ((unsigned)f2bf(a[c4 * 8 + 1]) << 16);
            pv.y = (unsigned)f2bf(a[c4 * 8 + 2]) | ((unsigned)f2bf(a[c4 * 8 + 3]) << 16);
            pv.z = (unsigned)f2bf(a[c4 * 8 + 4]) | ((unsigned)f2bf(a[c4 * 8 + 5]) << 16);
            pv.w = (unsigned)f2bf(a[c4 * 8 + 6]) | ((unsigned)f2bf(a[c4 * 8 + 7]) << 16);
            int c = sub * 4 + c4;
            *(uint4*)((char*)Asw + key * 256 + ((c ^ (key & 15)) << 4)) = pv;
        }
        __syncthreads();

        do_mfma(r);
        e0 = e0n; e1 = e1n;
    }

    // ---- epilogue: + bias, optional ReLU, store ----
    #pragma unroll
    for (int j = 0; j < NJ; j++) {
        int col = w * CW + j * 16 + r15;
        float bv = bias[col];
        #pragma unroll
        for (int i = 0; i < 4; i++) {
            #pragma unroll
            for (int reg = 0; reg < 4; reg++) {
                int m = n0 + i * 16 + q * 4 + reg;
                if (m < M) {
                    float v = acc[i][j][reg] + bv;
                    if (RELU) v = fmaxf(v, 0.f);
                    if (OUTBF16)
                        ((unsigned short*)outp)[(size_t)m * NOUT + col] = f2bf(v);
                    else
                        ((float*)outp)[(size_t)m * NOUT + col] = v;
                }
            }
        }
    }
}

extern "C" void kernel_launch(void* const* d_in, const int* in_sizes, int n_in,
                              void* d_out, int out_size, void* d_ws, size_t ws_size,
                              hipStream_t stream) {
    const float* X   = (const float*)d_in[0];
    const int*   src = (const int*)d_in[1];
    const int*   dst = (const int*)d_in[2];
    const int*   et  = (const int*)d_in[3];
    const float* W1  = (const float*)d_in[4];
    const float* W1s = (const float*)d_in[5];
    const float* b1  = (const float*)d_in[6];
    const float* W2  = (const float*)d_in[7];
    const float* W2s = (const float*)d_in[8];
    const float* b2  = (const float*)d_in[9];
    float* out = (float*)d_out;

    // workspace carve (~34 MB)
    char* p = (char*)d_ws;
    unsigned short* Xbf = (unsigned short*)p; p += (size_t)NN * 128 * 2;       // 12.8 MB
    unsigned short* hbf = (unsigned short*)p; p += (size_t)NN * 128 * 2;       // 12.8 MB
    unsigned short* W1T = (unsigned short*)p; p += (size_t)9 * 128 * 128 * 2;  // 288 KB
    unsigned short* W2T = (unsigned short*)p; p += (size_t)9 * 64 * 128 * 2;   // 144 KB
    int* counts2 = (int*)p; p += (size_t)NK * 4;                               // 1.6 MB
    int* off2    = (int*)p; p += (size_t)(NK + 4) * 4;                         // 1.6 MB
    int* cursor2 = (int*)p; p += (size_t)NK * 4;                               // 1.6 MB
    int* esrc    = (int*)p; p += (size_t)NE * 4;                               // 2.56 MB
    int* bsum    = (int*)p; p += 512 * 4;
    int* bbase   = (int*)p; p += 512 * 4;

    // ---- prep: memset + 3 launches, no grid.sync ----
    hipMemsetAsync(counts2, 0, (size_t)NK * sizeof(int), stream);
    prep0_kernel<<<2048, 256, 0, stream>>>(X, W1, W1s, W2, W2s, dst, et,
                                           Xbf, W1T, W2T, counts2);
    scanfused_kernel<<<NPB, 1024, 0, stream>>>(counts2, off2, cursor2, NK);
    fill2_kernel<<<(NE + 255) / 256, 256, 0, stream>>>(src, dst, et, cursor2, esrc);

    const int nblk = (NN + 63) / 64;  // 782

    // Layer 1: h = relu(agg1 + X@W1s + b1), stored bf16
    fused_layer<128, true, true><<<nblk, 256, 0, stream>>>(
        Xbf, W1T, b1, off2, esrc, hbf, NN);
    // Layer 2: out = agg2 + h@W2s + b2, fp32
    fused_layer<64, false, false><<<nblk, 256, 0, stream>>>(
        hbf, W2T, b2, off2, esrc, out, NN);
}

// Round 10
// 290.579 us; speedup vs baseline: 1.1527x; 1.1527x over previous
//
#include <hip/hip_runtime.h>
#include <hip/hip_bf16.h>
#include <stdint.h>

#define NN 50000     // nodes
#define NE 640000    // edges
#define NR 8         // relations
#define NK (NR * NN) // 400000 (rel,dst) keys
#define NPB 391      // scan blocks = ceil(NK/1024)

typedef short bf16x8 __attribute__((ext_vector_type(8)));
typedef float f32x4  __attribute__((ext_vector_type(4)));

__device__ __forceinline__ unsigned short f2bf(float f) {
    union { float f; unsigned u; } v; v.f = f;
    unsigned r = v.u + 0x7FFF + ((v.u >> 16) & 1);
    return (unsigned short)(r >> 16);
}

// ---------------- merged prep: HIST (counts pre-zeroed by memset) + cvt + prepW ----------------
// Atomics issued first; their retirement overlaps the 35MB of streaming below
// (no intra-kernel dependency). Removes hist2's standalone serial duration.
__global__ __launch_bounds__(256) void prep_hist_kernel(
        const float* __restrict__ X,
        const float* __restrict__ W1, const float* __restrict__ W1s,
        const float* __restrict__ W2, const float* __restrict__ W2s,
        const int* __restrict__ dst, const int* __restrict__ et,
        unsigned short* __restrict__ Xbf,
        unsigned short* __restrict__ W1T, unsigned short* __restrict__ W2T,
        int* __restrict__ counts) {
    const int gid = blockIdx.x * 256 + threadIdx.x;
    const int gsz = gridDim.x * 256;

    // histogram over (rel,dst) keys
    for (int e = gid; e < NE; e += gsz)
        atomicAdd(&counts[et[e] * NN + dst[e]], 1);

    // cvt X -> bf16, 8 floats per unit
    for (int i = gid; i < NN * 16; i += gsz) {
        const float4* pp = (const float4*)X + (size_t)i * 2;
        float4 a = pp[0], b = pp[1];
        uint4 o;
        o.x = (unsigned)f2bf(a.x) | ((unsigned)f2bf(a.y) << 16);
        o.y = (unsigned)f2bf(a.z) | ((unsigned)f2bf(a.w) << 16);
        o.z = (unsigned)f2bf(b.x) | ((unsigned)f2bf(b.y) << 16);
        o.w = (unsigned)f2bf(b.z) | ((unsigned)f2bf(b.w) << 16);
        ((uint4*)Xbf)[i] = o;
    }

    // W1T[(r*128+o)][k], r==8 -> W1s
    for (int i = gid; i < 9 * 128 * 128; i += gsz) {
        int k = i & 127, c = i >> 7;
        int r = c >> 7, o = c & 127;
        float v = (r < 8) ? W1[((size_t)r * 128 + k) * 128 + o]
                          : W1s[(size_t)k * 128 + o];
        W1T[i] = f2bf(v);
    }

    // W2T[(r*64+o)][k], r==8 -> W2s
    for (int i = gid; i < 9 * 64 * 128; i += gsz) {
        int k = i & 127, c = i >> 7;
        int r = c >> 6, o = c & 63;
        float v = (r < 8) ? W2[((size_t)r * 128 + k) * 64 + o]
                          : W2s[(size_t)k * 64 + o];
        W2T[i] = f2bf(v);
    }
}

// ---------------- CSR scan (r8-proven pair: blocksum + scanlocal2) ----------------
__global__ __launch_bounds__(1024) void blocksum_kernel(const int* __restrict__ counts,
                                                        int* __restrict__ bsum, int n) {
    __shared__ int ws[16];
    int i = blockIdx.x * 1024 + threadIdx.x;
    int v = (i < n) ? counts[i] : 0;
    #pragma unroll
    for (int d = 32; d > 0; d >>= 1) v += __shfl_down(v, d, 64);
    int wid = threadIdx.x >> 6, lane = threadIdx.x & 63;
    if (lane == 0) ws[wid] = v;
    __syncthreads();
    if (threadIdx.x < 16) {
        int s = ws[threadIdx.x];
        #pragma unroll
        for (int d = 8; d > 0; d >>= 1) s += __shfl_down(s, d, 16);
        if (threadIdx.x == 0) bsum[blockIdx.x] = s;
    }
}

// local scan + inline base (sums <=391 block sums per block — cheap)
__global__ __launch_bounds__(1024) void scanlocal2_kernel(const int* __restrict__ counts,
                                                          const int* __restrict__ bsum,
                                                          int* __restrict__ offsets,
                                                          int* __restrict__ cursor, int n) {
    __shared__ int ws[16];
    __shared__ int wbase[16];
    __shared__ int base_sh;
    const int t = threadIdx.x, b = blockIdx.x;
    const int i = b * 1024 + t;
    const int lane = t & 63, wid = t >> 6;

    int v = (i < n) ? counts[i] : 0;
    int incl = v;
    #pragma unroll
    for (int d = 1; d < 64; d <<= 1) {
        int nv = __shfl_up(incl, d, 64);
        if (lane >= d) incl += nv;
    }
    if (lane == 63) ws[wid] = incl;
    __syncthreads();
    if (t < 16) {
        int s = ws[t], si = s;
        #pragma unroll
        for (int d = 1; d < 16; d <<= 1) {
            int nv = __shfl_up(si, d, 16);
            if (t >= d) si += nv;
        }
        wbase[t] = si - s;
    }
    __syncthreads();
    int local_excl = wbase[wid] + incl - v;

    // wave 0: base = sum of bsum[0..b)
    if (wid == 0) {
        int acc = 0;
        for (int j = lane; j < b; j += 64) acc += bsum[j];
        #pragma unroll
        for (int d = 32; d > 0; d >>= 1) acc += __shfl_down(acc, d, 64);
        if (lane == 0) base_sh = acc;
    }
    __syncthreads();

    if (i < n) {
        int excl = base_sh + local_excl;
        offsets[i] = excl;
        cursor[i]  = excl;
    }
    if (b == 0 && t == 0) offsets[NK] = NE;
}

__global__ void fill2_kernel(const int* __restrict__ src, const int* __restrict__ dst,
                             const int* __restrict__ et, int* __restrict__ cursor,
                             int* __restrict__ esrc) {
    int e = blockIdx.x * 256 + threadIdx.x;
    if (e < NE) {
        int pos = atomicAdd(&cursor[et[e] * NN + dst[e]], 1);
        esrc[pos] = src[e];
    }
}

// ---------------- Fused aggregate + transform layer ----------------
// FROZEN: verified RB=64 shape (80.2 us/L1 measured r8/r9). Per block: 64 dst
// nodes, 256 threads. Edges sorted by (rel,dst): atomic-free aggregation.
// Thread t owns dst row (t>>2), column group (t&3): 32 cols in registers over
// its segment, packed to bf16 into the XOR-swizzled Asw. MFMA-accumulates
// C[64][NOUT] += agg_r @ W[r]^T across r=0..7 plus self (idx 8).
template<int NOUT, bool RELU, bool OUTBF16>
__global__ __launch_bounds__(256) void fused_layer(
        const unsigned short* __restrict__ A,    // [M][128] bf16 node features
        const unsigned short* __restrict__ WT,   // [9*NOUT][128] bf16
        const float* __restrict__ bias,          // [NOUT]
        const int* __restrict__ off2,            // [NK+1]
        const int* __restrict__ esrc,            // [NE] src sorted by (rel,dst)
        void* __restrict__ outp, int M) {
    constexpr int CW = NOUT / 4;      // cols per wave (MFMA)
    constexpr int NJ = CW / 16;       // n-tiles per wave
    __shared__ unsigned short Asw[64 * 128];    // swizzled bf16 A-operand (16 KB)

    const int t = threadIdx.x;
    const int n0 = blockIdx.x * 64;
    const int bm = (M - n0 < 64) ? (M - n0) : 64;
    const int lane = t & 63;
    const int w = t >> 6;
    const int r15 = lane & 15;
    const int q = lane >> 4;

    const int key = t >> 2;          // local dst row 0..63
    const int sub = t & 3;           // col group: uints [sub*16, sub*16+16)
    const int kk = n0 + key;
    const bool kv = (kk < M);

    f32x4 acc[4][NJ] = {};

    auto do_mfma = [&](int rr) {
        #pragma unroll
        for (int ks = 0; ks < 4; ks++) {
            int c = (ks * 4 + q) ^ r15;
            bf16x8 af[4];
            #pragma unroll
            for (int i = 0; i < 4; i++)
                af[i] = *(const bf16x8*)((const char*)Asw + (i * 16 + r15) * 256 + (c << 4));
            #pragma unroll
            for (int j = 0; j < NJ; j++) {
                bf16x8 bf = *(const bf16x8*)(WT +
                    ((size_t)(rr * NOUT + w * CW + j * 16 + r15) << 7) + ks * 32 + q * 8);
                #pragma unroll
                for (int i = 0; i < 4; i++)
                    acc[i][j] = __builtin_amdgcn_mfma_f32_16x16x32_bf16(af[i], bf, acc[i][j], 0, 0, 0);
            }
        }
    };

    // prefetch relation-0 segment bounds (off critical path of pass 0)
    int e0 = kv ? off2[kk] : 0;
    int e1 = kv ? off2[kk + 1] : 0;

    // ---- self pass (K-chunk index 8): Asw = own feature rows ----
    #pragma unroll
    for (int kc = 0; kc < 4; kc++) {
        int g = t + kc * 256;           // 1024 chunks = 64 rows x 16
        int row = g >> 4, c = g & 15;
        uint4 v = make_uint4(0, 0, 0, 0);
        if (row < bm) v = *(const uint4*)(A + ((size_t)(n0 + row) << 7) + c * 8);
        *(uint4*)((char*)Asw + row * 256 + ((c ^ (row & 15)) << 4)) = v;
    }
    __syncthreads();
    do_mfma(8);

    // ---- relation passes ----
    for (int r = 0; r < 8; r++) {
        // prefetch next relation's bounds (consumed next iteration)
        int e0n = 0, e1n = 0;
        if (r < 7 && kv) {
            e0n = off2[(r + 1) * NN + kk];
            e1n = off2[(r + 1) * NN + kk + 1];
        }

        // register-accumulate own segment (no LDS touched -> overlaps prior MFMA)
        float a[32];
        #pragma unroll
        for (int i = 0; i < 32; i++) a[i] = 0.f;
        for (int e = e0; e < e1; ++e) {
            int s = esrc[e];
            const uint4* rp = (const uint4*)((const unsigned*)A + ((size_t)s << 6) + sub * 16);
            #pragma unroll
            for (int u4 = 0; u4 < 4; ++u4) {
                uint4 v = rp[u4];
                unsigned uu[4] = {v.x, v.y, v.z, v.w};
                #pragma unroll
                for (int j = 0; j < 4; ++j) {
                    a[u4 * 8 + j * 2 + 0] += __uint_as_float(uu[j] << 16);
                    a[u4 * 8 + j * 2 + 1] += __uint_as_float(uu[j] & 0xffff0000u);
                }
            }
        }
        __syncthreads();   // all waves done reading Asw from previous MFMA

        // pack to bf16 and write 4 swizzled 16B chunks (c = sub*4+c4)
        #pragma unroll
        for (int c4 = 0; c4 < 4; ++c4) {
            uint4 pv;
            pv.x = (unsigned)f2bf(a[c4 * 8 + 0]) | ((unsigned)f2bf(a[c4 * 8 + 1]) << 16);
            pv.y = (unsigned)f2bf(a[c4 * 8 + 2]) | ((unsigned)f2bf(a[c4 * 8 + 3]) << 16);
            pv.z = (unsigned)f2bf(a[c4 * 8 + 4]) | ((unsigned)f2bf(a[c4 * 8 + 5]) << 16);
            pv.w = (unsigned)f2bf(a[c4 * 8 + 6]) | ((unsigned)f2bf(a[c4 * 8 + 7]) << 16);
            int c = sub * 4 + c4;
            *(uint4*)((char*)Asw + key * 256 + ((c ^ (key & 15)) << 4)) = pv;
        }
        __syncthreads();

        do_mfma(r);
        e0 = e0n; e1 = e1n;
    }

    // ---- epilogue: + bias, optional ReLU, store ----
    #pragma unroll
    for (int j = 0; j < NJ; j++) {
        int col = w * CW + j * 16 + r15;
        float bv = bias[col];
        #pragma unroll
        for (int i = 0; i < 4; i++) {
            #pragma unroll
            for (int reg = 0; reg < 4; reg++) {
                int m = n0 + i * 16 + q * 4 + reg;
                if (m < M) {
                    float v = acc[i][j][reg] + bv;
                    if (RELU) v = fmaxf(v, 0.f);
                    if (OUTBF16)
                        ((unsigned short*)outp)[(size_t)m * NOUT + col] = f2bf(v);
                    else
                        ((float*)outp)[(size_t)m * NOUT + col] = v;
                }
            }
        }
    }
}

extern "C" void kernel_launch(void* const* d_in, const int* in_sizes, int n_in,
                              void* d_out, int out_size, void* d_ws, size_t ws_size,
                              hipStream_t stream) {
    const float* X   = (const float*)d_in[0];
    const int*   src = (const int*)d_in[1];
    const int*   dst = (const int*)d_in[2];
    const int*   et  = (const int*)d_in[3];
    const float* W1  = (const float*)d_in[4];
    const float* W1s = (const float*)d_in[5];
    const float* b1  = (const float*)d_in[6];
    const float* W2  = (const float*)d_in[7];
    const float* W2s = (const float*)d_in[8];
    const float* b2  = (const float*)d_in[9];
    float* out = (float*)d_out;

    // workspace carve (~34 MB)
    char* p = (char*)d_ws;
    unsigned short* Xbf = (unsigned short*)p; p += (size_t)NN * 128 * 2;       // 12.8 MB
    unsigned short* hbf = (unsigned short*)p; p += (size_t)NN * 128 * 2;       // 12.8 MB
    unsigned short* W1T = (unsigned short*)p; p += (size_t)9 * 128 * 128 * 2;  // 288 KB
    unsigned short* W2T = (unsigned short*)p; p += (size_t)9 * 64 * 128 * 2;   // 144 KB
    int* counts2 = (int*)p; p += (size_t)NK * 4;                               // 1.6 MB
    int* off2    = (int*)p; p += (size_t)(NK + 4) * 4;                         // 1.6 MB
    int* cursor2 = (int*)p; p += (size_t)NK * 4;                               // 1.6 MB
    int* esrc    = (int*)p; p += (size_t)NE * 4;                               // 2.56 MB
    int* bsum    = (int*)p; p += 512 * 4;
    int* bbase   = (int*)p; p += 512 * 4;

    // ---- prep: memset + 4 launches, no grid.sync ----
    hipMemsetAsync(counts2, 0, (size_t)NK * sizeof(int), stream);
    prep_hist_kernel<<<2048, 256, 0, stream>>>(X, W1, W1s, W2, W2s, dst, et,
                                               Xbf, W1T, W2T, counts2);
    blocksum_kernel<<<NPB, 1024, 0, stream>>>(counts2, bsum, NK);
    scanlocal2_kernel<<<NPB, 1024, 0, stream>>>(counts2, bsum, off2, cursor2, NK);
    fill2_kernel<<<(NE + 255) / 256, 256, 0, stream>>>(src, dst, et, cursor2, esrc);

    const int nblk = (NN + 63) / 64;  // 782

    // Layer 1: h = relu(agg1 + X@W1s + b1), stored bf16
    fused_layer<128, true, true><<<nblk, 256, 0, stream>>>(
        Xbf, W1T, b1, off2, esrc, hbf, NN);
    // Layer 2: out = agg2 + h@W2s + b2, fp32
    fused_layer<64, false, false><<<nblk, 256, 0, stream>>>(
        hbf, W2T, b2, off2, esrc, out, NN);
}

// Round 14
// 285.285 us; speedup vs baseline: 1.1741x; 1.0186x over previous
//
#include <hip/hip_runtime.h>
#include <hip/hip_bf16.h>
#include <stdint.h>

#define NN 50000     // nodes
#define NE 640000    // edges
#define NR 8         // relations
#define NK (NR * NN) // 400000 (rel,dst) keys
#define NPB 391      // scan blocks = ceil(NK/1024)

typedef short bf16x8 __attribute__((ext_vector_type(8)));
typedef float f32x4  __attribute__((ext_vector_type(4)));

__device__ __forceinline__ unsigned short f2bf(float f) {
    union { float f; unsigned u; } v; v.f = f;
    unsigned r = v.u + 0x7FFF + ((v.u >> 16) & 1);
    return (unsigned short)(r >> 16);
}

// ---------------- merged prep: HIST + cvt (bf16 AND int8+rowscale) + prepW ----------------
// int8 path: per-row symmetric quantization q = rn(x * 127/rowmax), scale = rowmax/127.
// Row = 16 consecutive 8-elem units -> 16 consecutive lanes; rowmax via shfl_xor(1,2,4,8).
__global__ __launch_bounds__(256) void prep_hist_kernel(
        const float* __restrict__ X,
        const float* __restrict__ W1, const float* __restrict__ W1s,
        const float* __restrict__ W2, const float* __restrict__ W2s,
        const int* __restrict__ dst, const int* __restrict__ et,
        unsigned short* __restrict__ Xbf,
        unsigned char* __restrict__ Xq8, float* __restrict__ Xsc,
        unsigned short* __restrict__ W1T, unsigned short* __restrict__ W2T,
        int* __restrict__ counts) {
    const int gid = blockIdx.x * 256 + threadIdx.x;
    const int gsz = gridDim.x * 256;

    // histogram over (rel,dst) keys
    for (int e = gid; e < NE; e += gsz)
        atomicAdd(&counts[et[e] * NN + dst[e]], 1);

    // cvt X -> bf16 (exact copy) + int8 rowscaled (L1 gather copy)
    for (int i = gid; i < NN * 16; i += gsz) {
        const float4* pp = (const float4*)X + (size_t)i * 2;
        float4 a = pp[0], b = pp[1];
        float f[8] = {a.x, a.y, a.z, a.w, b.x, b.y, b.z, b.w};
        uint4 o;
        o.x = (unsigned)f2bf(f[0]) | ((unsigned)f2bf(f[1]) << 16);
        o.y = (unsigned)f2bf(f[2]) | ((unsigned)f2bf(f[3]) << 16);
        o.z = (unsigned)f2bf(f[4]) | ((unsigned)f2bf(f[5]) << 16);
        o.w = (unsigned)f2bf(f[6]) | ((unsigned)f2bf(f[7]) << 16);
        ((uint4*)Xbf)[i] = o;

        // rowmax over the 16 lanes sharing this row (lane group = i & 15)
        float mx = 0.f;
        #pragma unroll
        for (int j = 0; j < 8; j++) mx = fmaxf(mx, fabsf(f[j]));
        #pragma unroll
        for (int m = 1; m < 16; m <<= 1) mx = fmaxf(mx, __shfl_xor(mx, m, 64));
        float inv = (mx > 0.f) ? 127.f / mx : 0.f;
        int q[8];
        #pragma unroll
        for (int j = 0; j < 8; j++) q[j] = __float2int_rn(f[j] * inv);
        uint2 qp;
        qp.x = (q[0] & 0xFF) | ((q[1] & 0xFF) << 8) | ((q[2] & 0xFF) << 16) | ((unsigned)(q[3] & 0xFF) << 24);
        qp.y = (q[4] & 0xFF) | ((q[5] & 0xFF) << 8) | ((q[6] & 0xFF) << 16) | ((unsigned)(q[7] & 0xFF) << 24);
        ((uint2*)Xq8)[i] = qp;
        if ((i & 15) == 0) Xsc[i >> 4] = mx * (1.f / 127.f);
    }

    // W1T[(r*128+o)][k], r==8 -> W1s
    for (int i = gid; i < 9 * 128 * 128; i += gsz) {
        int k = i & 127, c = i >> 7;
        int r = c >> 7, o = c & 127;
        float v = (r < 8) ? W1[((size_t)r * 128 + k) * 128 + o]
                          : W1s[(size_t)k * 128 + o];
        W1T[i] = f2bf(v);
    }

    // W2T[(r*64+o)][k], r==8 -> W2s
    for (int i = gid; i < 9 * 64 * 128; i += gsz) {
        int k = i & 127, c = i >> 7;
        int r = c >> 6, o = c & 63;
        float v = (r < 8) ? W2[((size_t)r * 128 + k) * 64 + o]
                          : W2s[(size_t)k * 64 + o];
        W2T[i] = f2bf(v);
    }
}

// ---------------- CSR scan (r8-proven pair) ----------------
__global__ __launch_bounds__(1024) void blocksum_kernel(const int* __restrict__ counts,
                                                        int* __restrict__ bsum, int n) {
    __shared__ int ws[16];
    int i = blockIdx.x * 1024 + threadIdx.x;
    int v = (i < n) ? counts[i] : 0;
    #pragma unroll
    for (int d = 32; d > 0; d >>= 1) v += __shfl_down(v, d, 64);
    int wid = threadIdx.x >> 6, lane = threadIdx.x & 63;
    if (lane == 0) ws[wid] = v;
    __syncthreads();
    if (threadIdx.x < 16) {
        int s = ws[threadIdx.x];
        #pragma unroll
        for (int d = 8; d > 0; d >>= 1) s += __shfl_down(s, d, 16);
        if (threadIdx.x == 0) bsum[blockIdx.x] = s;
    }
}

__global__ __launch_bounds__(1024) void scanlocal2_kernel(const int* __restrict__ counts,
                                                          const int* __restrict__ bsum,
                                                          int* __restrict__ offsets,
                                                          int* __restrict__ cursor, int n) {
    __shared__ int ws[16];
    __shared__ int wbase[16];
    __shared__ int base_sh;
    const int t = threadIdx.x, b = blockIdx.x;
    const int i = b * 1024 + t;
    const int lane = t & 63, wid = t >> 6;

    int v = (i < n) ? counts[i] : 0;
    int incl = v;
    #pragma unroll
    for (int d = 1; d < 64; d <<= 1) {
        int nv = __shfl_up(incl, d, 64);
        if (lane >= d) incl += nv;
    }
    if (lane == 63) ws[wid] = incl;
    __syncthreads();
    if (t < 16) {
        int s = ws[t], si = s;
        #pragma unroll
        for (int d = 1; d < 16; d <<= 1) {
            int nv = __shfl_up(si, d, 16);
            if (t >= d) si += nv;
        }
        wbase[t] = si - s;
    }
    __syncthreads();
    int local_excl = wbase[wid] + incl - v;

    if (wid == 0) {
        int acc = 0;
        for (int j = lane; j < b; j += 64) acc += bsum[j];
        #pragma unroll
        for (int d = 32; d > 0; d >>= 1) acc += __shfl_down(acc, d, 64);
        if (lane == 0) base_sh = acc;
    }
    __syncthreads();

    if (i < n) {
        int excl = base_sh + local_excl;
        offsets[i] = excl;
        cursor[i]  = excl;
    }
    if (b == 0 && t == 0) offsets[NK] = NE;
}

__global__ void fill2_kernel(const int* __restrict__ src, const int* __restrict__ dst,
                             const int* __restrict__ et, int* __restrict__ cursor,
                             int* __restrict__ esrc) {
    int e = blockIdx.x * 256 + threadIdx.x;
    if (e < NE) {
        int pos = atomicAdd(&cursor[et[e] * NN + dst[e]], 1);
        esrc[pos] = src[e];
    }
}

// ---------------- Fused aggregate + transform layer ----------------
// RB=64 verified shape (80.2us). GQ8: L1 gathers the int8+rowscale copy
// (128B/row = 2 cache lines vs 4; decode = shl/ashr/cvt/fma per elem).
// L2 gathers bf16 h exactly (fp8-class quant on h failed absmax r11/r12).
template<int NOUT, bool RELU, bool OUTBF16, bool GQ8>
__global__ __launch_bounds__(256) void fused_layer(
        const unsigned short* __restrict__ A,    // [M][128] bf16 node features
        const unsigned char*  __restrict__ Aq,   // [M][128] int8 gather copy (GQ8)
        const float* __restrict__ Asc,           // [M] row scales (GQ8)
        const unsigned short* __restrict__ WT,   // [9*NOUT][128] bf16
        const float* __restrict__ bias,          // [NOUT]
        const int* __restrict__ off2,            // [NK+1]
        const int* __restrict__ esrc,            // [NE] src sorted by (rel,dst)
        void* __restrict__ outp,                 // bf16 (L1) or f32 (L2)
        int M) {
    constexpr int CW = NOUT / 4;      // cols per wave (MFMA)
    constexpr int NJ = CW / 16;       // n-tiles per wave
    __shared__ unsigned short Asw[64 * 128];    // swizzled bf16 A-operand (16 KB)

    const int t = threadIdx.x;
    const int n0 = blockIdx.x * 64;
    const int bm = (M - n0 < 64) ? (M - n0) : 64;
    const int lane = t & 63;
    const int w = t >> 6;
    const int r15 = lane & 15;
    const int q = lane >> 4;

    const int key = t >> 2;          // local dst row 0..63
    const int sub = t & 3;           // col group: cols [sub*32, sub*32+32)
    const int kk = n0 + key;
    const bool kv = (kk < M);

    f32x4 acc[4][NJ] = {};

    auto do_mfma = [&](int rr) {
        #pragma unroll
        for (int ks = 0; ks < 4; ks++) {
            int c = (ks * 4 + q) ^ r15;
            bf16x8 af[4];
            #pragma unroll
            for (int i = 0; i < 4; i++)
                af[i] = *(const bf16x8*)((const char*)Asw + (i * 16 + r15) * 256 + (c << 4));
            #pragma unroll
            for (int j = 0; j < NJ; j++) {
                bf16x8 bf = *(const bf16x8*)(WT +
                    ((size_t)(rr * NOUT + w * CW + j * 16 + r15) << 7) + ks * 32 + q * 8);
                #pragma unroll
                for (int i = 0; i < 4; i++)
                    acc[i][j] = __builtin_amdgcn_mfma_f32_16x16x32_bf16(af[i], bf, acc[i][j], 0, 0, 0);
            }
        }
    };

    // prefetch relation-0 segment bounds (off critical path of pass 0)
    int e0 = kv ? off2[kk] : 0;
    int e1 = kv ? off2[kk + 1] : 0;

    // ---- self pass (K-chunk index 8): Asw = own feature rows (bf16 exact) ----
    #pragma unroll
    for (int kc = 0; kc < 4; kc++) {
        int g = t + kc * 256;           // 1024 chunks = 64 rows x 16
        int row = g >> 4, c = g & 15;
        uint4 v = make_uint4(0, 0, 0, 0);
        if (row < bm) v = *(const uint4*)(A + ((size_t)(n0 + row) << 7) + c * 8);
        *(uint4*)((char*)Asw + row * 256 + ((c ^ (row & 15)) << 4)) = v;
    }
    __syncthreads();
    do_mfma(8);

    // ---- relation passes ----
    for (int r = 0; r < 8; r++) {
        // prefetch next relation's bounds (consumed next iteration)
        int e0n = 0, e1n = 0;
        if (r < 7 && kv) {
            e0n = off2[(r + 1) * NN + kk];
            e1n = off2[(r + 1) * NN + kk + 1];
        }

        // register-accumulate own segment
        float a[32];
        #pragma unroll
        for (int i = 0; i < 32; i++) a[i] = 0.f;
        for (int e = e0; e < e1; ++e) {
            int s = esrc[e];
            if (GQ8) {
                // int8 gather: 32B/thread (2 uint4 of the 128B row) + row scale
                float sc = Asc[s];
                const uint4* rp = (const uint4*)(Aq + ((size_t)s << 7) + sub * 32);
                uint4 q0 = rp[0], q1 = rp[1];
                unsigned uu[8] = {q0.x, q0.y, q0.z, q0.w, q1.x, q1.y, q1.z, q1.w};
                #pragma unroll
                for (int d = 0; d < 8; ++d) {
                    unsigned x = uu[d];
                    a[d * 4 + 0] = fmaf((float)((int)(x << 24) >> 24), sc, a[d * 4 + 0]);
                    a[d * 4 + 1] = fmaf((float)((int)(x << 16) >> 24), sc, a[d * 4 + 1]);
                    a[d * 4 + 2] = fmaf((float)((int)(x <<  8) >> 24), sc, a[d * 4 + 2]);
                    a[d * 4 + 3] = fmaf((float)((int)x >> 24),         sc, a[d * 4 + 3]);
                }
            } else {
                // bf16 gather (exact)
                const uint4* rp = (const uint4*)((const unsigned*)A + ((size_t)s << 6) + sub * 16);
                #pragma unroll
                for (int u4 = 0; u4 < 4; ++u4) {
                    uint4 v = rp[u4];
                    unsigned uu[4] = {v.x, v.y, v.z, v.w};
                    #pragma unroll
                    for (int j = 0; j < 4; ++j) {
                        a[u4 * 8 + j * 2 + 0] += __uint_as_float(uu[j] << 16);
                        a[u4 * 8 + j * 2 + 1] += __uint_as_float(uu[j] & 0xffff0000u);
                    }
                }
            }
        }
        __syncthreads();   // all waves done reading Asw from previous MFMA

        // pack to bf16 and write 4 swizzled 16B chunks (c = sub*4+c4)
        #pragma unroll
        for (int c4 = 0; c4 < 4; ++c4) {
            uint4 pv;
            pv.x = (unsigned)f2bf(a[c4 * 8 + 0]) | ((unsigned)f2bf(a[c4 * 8 + 1]) << 16);
            pv.y = (unsigned)f2bf(a[c4 * 8 + 2]) | ((unsigned)f2bf(a[c4 * 8 + 3]) << 16);
            pv.z = (unsigned)f2bf(a[c4 * 8 + 4]) | ((unsigned)f2bf(a[c4 * 8 + 5]) << 16);
            pv.w = (unsigned)f2bf(a[c4 * 8 + 6]) | ((unsigned)f2bf(a[c4 * 8 + 7]) << 16);
            int c = sub * 4 + c4;
            *(uint4*)((char*)Asw + key * 256 + ((c ^ (key & 15)) << 4)) = pv;
        }
        __syncthreads();

        do_mfma(r);
        e0 = e0n; e1 = e1n;
    }

    // ---- epilogue: + bias, optional ReLU, store ----
    #pragma unroll
    for (int j = 0; j < NJ; j++) {
        int col = w * CW + j * 16 + r15;
        float bv = bias[col];
        #pragma unroll
        for (int i = 0; i < 4; i++) {
            #pragma unroll
            for (int reg = 0; reg < 4; reg++) {
                int m = n0 + i * 16 + q * 4 + reg;
                if (m < M) {
                    float v = acc[i][j][reg] + bv;
                    if (RELU) v = fmaxf(v, 0.f);
                    if (OUTBF16)
                        ((unsigned short*)outp)[(size_t)m * NOUT + col] = f2bf(v);
                    else
                        ((float*)outp)[(size_t)m * NOUT + col] = v;
                }
            }
        }
    }
}

extern "C" void kernel_launch(void* const* d_in, const int* in_sizes, int n_in,
                              void* d_out, int out_size, void* d_ws, size_t ws_size,
                              hipStream_t stream) {
    const float* X   = (const float*)d_in[0];
    const int*   src = (const int*)d_in[1];
    const int*   dst = (const int*)d_in[2];
    const int*   et  = (const int*)d_in[3];
    const float* W1  = (const float*)d_in[4];
    const float* W1s = (const float*)d_in[5];
    const float* b1  = (const float*)d_in[6];
    const float* W2  = (const float*)d_in[7];
    const float* W2s = (const float*)d_in[8];
    const float* b2  = (const float*)d_in[9];
    float* out = (float*)d_out;

    // workspace carve (~41 MB)
    char* p = (char*)d_ws;
    unsigned short* Xbf = (unsigned short*)p; p += (size_t)NN * 128 * 2;       // 12.8 MB
    unsigned short* hbf = (unsigned short*)p; p += (size_t)NN * 128 * 2;       // 12.8 MB
    unsigned short* W1T = (unsigned short*)p; p += (size_t)9 * 128 * 128 * 2;  // 288 KB
    unsigned short* W2T = (unsigned short*)p; p += (size_t)9 * 64 * 128 * 2;   // 144 KB
    int* counts2 = (int*)p; p += (size_t)NK * 4;                               // 1.6 MB
    int* off2    = (int*)p; p += (size_t)(NK + 4) * 4;                         // 1.6 MB
    int* cursor2 = (int*)p; p += (size_t)NK * 4;                               // 1.6 MB
    int* esrc    = (int*)p; p += (size_t)NE * 4;                               // 2.56 MB
    int* bsum    = (int*)p; p += 512 * 4;
    int* bbase   = (int*)p; p += 512 * 4;
    unsigned char* Xq8 = (unsigned char*)p; p += (size_t)NN * 128;             // 6.4 MB
    float* Xsc = (float*)p; p += (size_t)NN * 4;                               // 200 KB

    // ---- prep: memset + 4 launches, no grid.sync ----
    hipMemsetAsync(counts2, 0, (size_t)NK * sizeof(int), stream);
    prep_hist_kernel<<<2048, 256, 0, stream>>>(X, W1, W1s, W2, W2s, dst, et,
                                               Xbf, Xq8, Xsc, W1T, W2T, counts2);
    blocksum_kernel<<<NPB, 1024, 0, stream>>>(counts2, bsum, NK);
    scanlocal2_kernel<<<NPB, 1024, 0, stream>>>(counts2, bsum, off2, cursor2, NK);
    fill2_kernel<<<(NE + 255) / 256, 256, 0, stream>>>(src, dst, et, cursor2, esrc);

    const int nblk = (NN + 63) / 64;  // 782

    // Layer 1: h = relu(agg1(int8 gather) + X@W1s + b1), stored bf16
    fused_layer<128, true, true, true><<<nblk, 256, 0, stream>>>(
        Xbf, Xq8, Xsc, W1T, b1, off2, esrc, hbf, NN);
    // Layer 2: out = agg2(bf16 gather) + h@W2s + b2, fp32
    fused_layer<64, false, false, false><<<nblk, 256, 0, stream>>>(
        hbf, nullptr, nullptr, W2T, b2, off2, esrc, out, NN);
}